// Round 1
// baseline (1617.803 us; speedup 1.0000x reference)
//
#include <hip/hip_runtime.h>

// TitansMemory: per-row delta-rule-with-momentum scan. B=16, L=8192, DK=DV=128.
// 2048 independent rows (b,v):
//   s = C_S*(w·k - v) ; m̂ = β m̂ + s k   (m̂ = -lr m, C_S = -2 lr (1-β))
//   w = (1-α) w + m̂   ; y = w·q
// Mapping: ONE row per wave, 2 cols/lane (f2), 2048 single-wave blocks
// = 8 waves/CU = 2 waves/SIMD.
// Round 6 change: reduction is now a full all-lane VALU butterfly:
//   4x fused DPP row_ror adds (row-of-16 sums in all lanes)
//   + v_permlane16_swap_b32 + add   (cross-row-16 pairwise sums)
//   + v_permlane32_swap_b32 + add   (cross-half sums -> total in ALL lanes)
// This removes both v_readlane->SGPR->VALU round-trips from the step
// (one of which sat on the serial w-recurrence chain). s is now a per-lane
// VGPR; y is selected per-lane with cndmask as before.
// Memory: A/B ping-pong register frag buffers (8+8 deep), no LDS.

#define B_ 16
#define L_ 8192
#define D_ 128
#define CH 8  // half-chunk depth (A/B buffers)

typedef __attribute__((ext_vector_type(2))) float f2;
typedef __attribute__((ext_vector_type(2))) unsigned int u2;

constexpr float A_    = 0.98f;
constexpr float BETA_ = 0.9f;
constexpr float C_S   = -(2.0f * 0.1f * 0.1f);  // -2*lr*(1-beta) = -0.02

template <int CTRL>
__device__ __forceinline__ float dpp_add(float x) {
  int y = __builtin_amdgcn_update_dpp(0, __float_as_int(x), CTRL, 0xF, 0xF, true);
  return x + __int_as_float(y);
}

// Full 64-lane sum, result valid in EVERY lane, pure VALU (no readlane/SGPR).
__device__ __forceinline__ float wave_sum_all(float x) {
  x = dpp_add<0x121>(x);  // row_ror:1
  x = dpp_add<0x122>(x);  // row_ror:2
  x = dpp_add<0x124>(x);  // row_ror:4
  x = dpp_add<0x128>(x);  // row_ror:8  -> each lane holds its row-of-16 sum
  // cross row-16 within each 32-half: both outputs of the swap together
  // cover {own row, other row} for every lane -> add them.
  u2 p16 = __builtin_amdgcn_permlane16_swap(__float_as_uint(x), __float_as_uint(x),
                                            false, false);
  x = __uint_as_float(p16.x) + __uint_as_float(p16.y);
  // cross 32-halves: same trick.
  u2 p32 = __builtin_amdgcn_permlane32_swap(__float_as_uint(x), __float_as_uint(x),
                                            false, false);
  return __uint_as_float(p32.x) + __uint_as_float(p32.y);
}

struct Frag {
  f2 k, q;   // this lane's 2 cols of k_t, q_t
  float v;   // v[t, row] (wave-uniform broadcast load)
};

__global__ __launch_bounds__(64, 2)
void TitansMemory_188978561365_kernel(const float* __restrict__ Q,
                                      const float* __restrict__ K,
                                      const float* __restrict__ V,
                                      float* __restrict__ Y) {
  const int lane  = threadIdx.x;        // 0..63
  const int wid   = blockIdx.x;         // 0..2047
  const int batch = wid >> 7;           // 128 rows per batch
  const int row   = wid & 127;

  const size_t bbase = (size_t)batch * (size_t)L_ * D_;
  const float* Kp = K + bbase + lane * 2;
  const float* Qp = Q + bbase + lane * 2;
  const float* Vp = V + bbase + row;
  float*       Yp = Y + bbase + row;    // + (t-window*64 + lane)*D_

  auto ld = [&](int t) -> Frag {
    int tc = (t < L_) ? t : (L_ - 1);   // clamp tail prefetch
    Frag f;
    f.k = *(const f2*)(Kp + (size_t)tc * D_);
    f.q = *(const f2*)(Qp + (size_t)tc * D_);
    f.v = Vp[(size_t)tc * D_];
    return f;
  };

  const f2 av = {A_, A_};
  const f2 bv = {BETA_, BETA_};

  f2 w = {0.f, 0.f}, m = {0.f, 0.f};
  float yl = 0.f;

  auto step = [&](const Frag& f, int t) {
    // ---- dot = w·k  (serial chain; all-lane VALU butterfly) ----
    f2 d = w * f.k;
    float dot = wave_sum_all(d.x + d.y);
    float vneg = (-C_S) * f.v;              // off-chain
    float s = fmaf(C_S, dot, vneg);         // per-lane (identical in all lanes)
    f2 s2 = {s, s};

    // ---- m̂ = β m̂ + s k ; w = A w + m̂  (packed f32) ----
    m = __builtin_elementwise_fma(s2, f.k, bv * m);
    w = __builtin_elementwise_fma(av, w, m);

    // ---- y = w·q  (off the serial chain) ----
    f2 e = w * f.q;
    float y = wave_sum_all(e.x + e.y);

    // lane (t&63) keeps y_t (y is identical in all lanes); one store / 64 steps.
    yl = (lane == (t & 63)) ? y : yl;
    if ((t & 63) == 63) {
      Yp[(size_t)((t & ~63) + lane) * D_] = yl;
    }
  };

  // Prologue: fill both frag buffers (steps 0..15).
  Frag fa[CH], fb[CH];
#pragma unroll
  for (int j = 0; j < CH; ++j) fa[j] = ld(j);
#pragma unroll
  for (int j = 0; j < CH; ++j) fb[j] = ld(CH + j);

  for (int tb = 0; tb < L_; tb += 2 * CH) {
#pragma unroll
    for (int j = 0; j < CH; ++j) step(fa[j], tb + j);
#pragma unroll
    for (int j = 0; j < CH; ++j) fa[j] = ld(tb + 2 * CH + j);
    __builtin_amdgcn_sched_barrier(0);  // loads stay ahead of the B-half
#pragma unroll
    for (int j = 0; j < CH; ++j) step(fb[j], tb + CH + j);
#pragma unroll
    for (int j = 0; j < CH; ++j) fb[j] = ld(tb + 3 * CH + j);
    __builtin_amdgcn_sched_barrier(0);  // loads stay ahead of the backedge
  }
}

extern "C" void kernel_launch(void* const* d_in, const int* in_sizes, int n_in,
                              void* d_out, int out_size, void* d_ws, size_t ws_size,
                              hipStream_t stream) {
  const float* Q = (const float*)d_in[0];
  const float* K = (const float*)d_in[1];
  const float* V = (const float*)d_in[2];
  float* Y = (float*)d_out;
  dim3 grid(2048), block(64);
  hipLaunchKernelGGL(TitansMemory_188978561365_kernel, grid, block, 0, stream,
                     Q, K, V, Y);
}

// Round 2
// 1389.309 us; speedup vs baseline: 1.1645x; 1.1645x over previous
//
#include <hip/hip_runtime.h>

// TitansMemory: per-row delta-rule-with-momentum scan. B=16, L=8192, DK=DV=128.
// 2048 independent rows (b,v):
//   s = C_S*(w·k - v) ; m̂ = β m̂ + s k   (m̂ = -lr m, C_S = -2 lr (1-β))
//   w = (1-α) w + m̂   ; y = w·q
// Round 7 mapping: TWO rows per wave. Lanes 0-31 own row0, lanes 32-63 own
// row1; each lane holds 4 consecutive k-columns (f4). Reduction is a 32-lane
// half-wave butterfly (4x fused DPP row_ror + permlane16_swap+add) that
// reduces BOTH rows simultaneously -> per-row reduction cost drops 16->3
// issue slots. Elementwise m/w updates and k/q loads amortize 2x.
// 1024 single-wave blocks = 4 waves/CU = 1 wave/SIMD (the bet: issue count
// per row halves, chain is short enough to eat the lost interleaving).
// Memory: A/B ping-pong register frag buffers (8+8 deep), no LDS.

#define B_ 16
#define L_ 8192
#define D_ 128
#define CH 8  // half-chunk depth (A/B buffers)

typedef __attribute__((ext_vector_type(4))) float f4;
typedef __attribute__((ext_vector_type(2))) unsigned int u2;

constexpr float A_    = 0.98f;
constexpr float BETA_ = 0.9f;
constexpr float C_S   = -(2.0f * 0.1f * 0.1f);  // -2*lr*(1-beta) = -0.02

template <int CTRL>
__device__ __forceinline__ float dpp_add(float x) {
  int y = __builtin_amdgcn_update_dpp(0, __float_as_int(x), CTRL, 0xF, 0xF, true);
  return x + __int_as_float(y);
}

// Half-wave (32-lane) all-reduce: lanes 0-31 end with sum over lanes 0-31,
// lanes 32-63 with sum over lanes 32-63. Pure VALU.
__device__ __forceinline__ float half_sum_all(float x) {
  x = dpp_add<0x121>(x);  // row_ror:1
  x = dpp_add<0x122>(x);  // row_ror:2
  x = dpp_add<0x124>(x);  // row_ror:4
  x = dpp_add<0x128>(x);  // row_ror:8  -> each lane holds its row-of-16 sum
  // combine lane^16 (rows 0<->1 and 2<->3) : p.x + p.y = x[lane] + x[lane^16]
  u2 p = __builtin_amdgcn_permlane16_swap(__float_as_uint(x), __float_as_uint(x),
                                          false, false);
  return __uint_as_float(p.x) + __uint_as_float(p.y);
}

struct Frag {
  f4 k, q;   // this lane's 4 cols of k_t, q_t
  float v;   // v[t, row] (uniform within each 32-lane half)
};

__global__ __launch_bounds__(64, 1)
void TitansMemory_188978561365_kernel(const float* __restrict__ Q,
                                      const float* __restrict__ K,
                                      const float* __restrict__ V,
                                      float* __restrict__ Y) {
  const int lane  = threadIdx.x;              // 0..63
  const int wid   = blockIdx.x;               // 0..1023
  const int batch = wid >> 6;                 // 64 waves per batch (128 rows)
  const int row   = ((wid & 63) << 1) | (lane >> 5);  // 2 rows per wave
  const int col   = (lane & 31) << 2;         // 4 k-cols per lane

  const size_t bbase = (size_t)batch * (size_t)L_ * D_;
  const float* Kp = K + bbase + col;
  const float* Qp = Q + bbase + col;
  const float* Vp = V + bbase + row;
  float*       Yp = Y + bbase + row;          // + (t0 + lane&31)*D_

  auto ld = [&](int t) -> Frag {
    int tc = (t < L_) ? t : (L_ - 1);         // clamp tail prefetch
    Frag f;
    f.k = *(const f4*)(Kp + (size_t)tc * D_);
    f.q = *(const f4*)(Qp + (size_t)tc * D_);
    f.v = Vp[(size_t)tc * D_];
    return f;
  };

  const f4 av = {A_, A_, A_, A_};
  const f4 bv = {BETA_, BETA_, BETA_, BETA_};

  f4 w = {0.f, 0.f, 0.f, 0.f}, m = {0.f, 0.f, 0.f, 0.f};
  float yl = 0.f;

  auto step = [&](const Frag& f, int t) {
    // ---- dot = w·k  (serial chain; half-wave butterfly serves both rows) ----
    f4 d = w * f.k;
    float dot = half_sum_all((d.x + d.y) + (d.z + d.w));
    float vneg = (-C_S) * f.v;              // off-chain
    float s = fmaf(C_S, dot, vneg);         // per-lane (uniform within half)
    f4 s4 = {s, s, s, s};

    // ---- m̂ = β m̂ + s k ; w = A w + m̂  (packed f32, 2 rows at once) ----
    m = __builtin_elementwise_fma(s4, f.k, bv * m);
    w = __builtin_elementwise_fma(av, w, m);

    // ---- y = w·q  (off the serial chain) ----
    f4 e = w * f.q;
    float y = half_sum_all((e.x + e.y) + (e.z + e.w));

    // lane (t&31) of each half keeps y_t; one store per 32 steps (64 values:
    // 2 rows x 32 timesteps).
    yl = ((lane & 31) == (t & 31)) ? y : yl;
    if ((t & 31) == 31) {
      Yp[(size_t)((t & ~31) + (lane & 31)) * D_] = yl;
    }
  };

  // Prologue: fill both frag buffers (steps 0..15).
  Frag fa[CH], fb[CH];
#pragma unroll
  for (int j = 0; j < CH; ++j) fa[j] = ld(j);
#pragma unroll
  for (int j = 0; j < CH; ++j) fb[j] = ld(CH + j);

  for (int tb = 0; tb < L_; tb += 2 * CH) {
#pragma unroll
    for (int j = 0; j < CH; ++j) step(fa[j], tb + j);
#pragma unroll
    for (int j = 0; j < CH; ++j) fa[j] = ld(tb + 2 * CH + j);
    __builtin_amdgcn_sched_barrier(0);  // loads stay ahead of the B-half
#pragma unroll
    for (int j = 0; j < CH; ++j) step(fb[j], tb + CH + j);
#pragma unroll
    for (int j = 0; j < CH; ++j) fb[j] = ld(tb + 3 * CH + j);
    __builtin_amdgcn_sched_barrier(0);  // loads stay ahead of the backedge
  }
}

extern "C" void kernel_launch(void* const* d_in, const int* in_sizes, int n_in,
                              void* d_out, int out_size, void* d_ws, size_t ws_size,
                              hipStream_t stream) {
  const float* Q = (const float*)d_in[0];
  const float* K = (const float*)d_in[1];
  const float* V = (const float*)d_in[2];
  float* Y = (float*)d_out;
  dim3 grid(1024), block(64);
  hipLaunchKernelGGL(TitansMemory_188978561365_kernel, grid, block, 0, stream,
                     Q, K, V, Y);
}

// Round 3
// 1098.365 us; speedup vs baseline: 1.4729x; 1.2649x over previous
//
#include <hip/hip_runtime.h>

// TitansMemory: per-row delta-rule-with-momentum scan. B=16, L=8192, DK=DV=128.
//   s = C_S*(w·k - v) ; m̂ = β m̂ + s k ; w = (1-α) w + m̂ ; y = w·q
// Mapping (round 7): TWO rows per wave (lanes 0-31 row0, 32-63 row1), 4 cols
// per lane (f4). 1024 single-wave blocks = 1 wave/SIMD -> VGPRs are free
// (up to 512); latency must be hidden by software pipelining, not TLP.
// Round 8 change: the compiler was sinking the prefetch buffers (VGPR=88 vs
// the 144+ floats the pipeline needs) -> each 8-step chunk ate exposed L2/HBM
// latency (VALUBusy 44%, 215 stall cyc/step). Loads are now PINNED with
// asm volatile global_load into named register buffers, with counted
// s_waitcnt vmcnt(24) + sched_barrier(0) (two 8-step chunks of 24 loads in
// flight), and immediate-offset addressing (offset:j*512, one 64-bit address
// bump per chunk) replacing per-load clamp+address math.

#define L_ 8192
#define D_ 128

typedef __attribute__((ext_vector_type(4))) float f4;
typedef __attribute__((ext_vector_type(2))) unsigned int u2;

constexpr float A_    = 0.98f;
constexpr float BETA_ = 0.9f;
constexpr float C_S   = -0.02f;  // -2*lr*(1-beta)

template <int CTRL>
__device__ __forceinline__ float dpp_add(float x) {
  int y = __builtin_amdgcn_update_dpp(0, __float_as_int(x), CTRL, 0xF, 0xF, true);
  return x + __int_as_float(y);
}

// Half-wave (32-lane) all-reduce: lanes 0-31 -> sum over lanes 0-31,
// lanes 32-63 -> sum over lanes 32-63. Pure VALU. (Harness-verified r1/r2.)
__device__ __forceinline__ float half_sum_all(float x) {
  x = dpp_add<0x121>(x);  // row_ror:1
  x = dpp_add<0x122>(x);  // row_ror:2
  x = dpp_add<0x124>(x);  // row_ror:4
  x = dpp_add<0x128>(x);  // row_ror:8
  u2 p = __builtin_amdgcn_permlane16_swap(__float_as_uint(x), __float_as_uint(x),
                                          false, false);
  return __uint_as_float(p.x) + __uint_as_float(p.y);
}

// Pinned loads: asm volatile keeps issue placement and register residency.
#define GLD4(dst, addr, OFF) \
  asm volatile("global_load_dwordx4 %0, %1, off offset:" OFF : "=v"(dst) : "v"(addr))
#define GLD1(dst, addr, OFF) \
  asm volatile("global_load_dword %0, %1, off offset:" OFF : "=v"(dst) : "v"(addr))

// One 8-step chunk: 24 loads (8x K f4, 8x Q f4, 8x V f1), then bump addresses
// by one chunk (4096 B) unless the next chunk would run past L (clamp: tail
// prefetches re-read chunk 1023's rows; their data is never consumed).
#define ISSUE_CHUNK(kb, qb, vb)                            \
  do {                                                     \
    GLD4(kb[0], ka64, "0");    GLD4(qb[0], qa64, "0");    GLD1(vb[0], va64, "0");    \
    GLD4(kb[1], ka64, "512");  GLD4(qb[1], qa64, "512");  GLD1(vb[1], va64, "512");  \
    GLD4(kb[2], ka64, "1024"); GLD4(qb[2], qa64, "1024"); GLD1(vb[2], va64, "1024"); \
    GLD4(kb[3], ka64, "1536"); GLD4(qb[3], qa64, "1536"); GLD1(vb[3], va64, "1536"); \
    GLD4(kb[4], ka64, "2048"); GLD4(qb[4], qa64, "2048"); GLD1(vb[4], va64, "2048"); \
    GLD4(kb[5], ka64, "2560"); GLD4(qb[5], qa64, "2560"); GLD1(vb[5], va64, "2560"); \
    GLD4(kb[6], ka64, "3072"); GLD4(qb[6], qa64, "3072"); GLD1(vb[6], va64, "3072"); \
    GLD4(kb[7], ka64, "3584"); GLD4(qb[7], qa64, "3584"); GLD1(vb[7], va64, "3584"); \
    uint64_t bump_ = (sc < 1023) ? 4096u : 0u;             \
    ka64 += bump_; qa64 += bump_; va64 += bump_; ++sc;     \
  } while (0)

// Wait until only the younger chunk's 24 loads remain, then fence the
// scheduler so no consumer is hoisted above the wait (guide rule 18).
#define WAITP                                              \
  do {                                                     \
    asm volatile("s_waitcnt vmcnt(24)");                   \
    __builtin_amdgcn_sched_barrier(0);                     \
  } while (0)

__global__ __launch_bounds__(64, 1)
void TitansMemory_188978561365_kernel(const float* __restrict__ Q,
                                      const float* __restrict__ K,
                                      const float* __restrict__ V,
                                      float* __restrict__ Y) {
  const int lane  = threadIdx.x;              // 0..63
  const int wid   = blockIdx.x;               // 0..1023
  const int batch = wid >> 6;                 // 64 waves per batch (128 rows)
  const int row   = ((wid & 63) << 1) | (lane >> 5);  // 2 rows per wave
  const int col   = (lane & 31) << 2;         // 4 k-cols per lane

  const size_t bbase = (size_t)batch * (size_t)L_ * D_;
  uint64_t ka64 = (uint64_t)(K + bbase + col);
  uint64_t qa64 = (uint64_t)(Q + bbase + col);
  uint64_t va64 = (uint64_t)(V + bbase + row);
  float*   yst  = Y + bbase + row + (size_t)(lane & 31) * D_;
  int sc = 0;  // chunks issued so far (for the tail clamp)

  const f4 av = {A_, A_, A_, A_};
  const f4 bv = {BETA_, BETA_, BETA_, BETA_};

  f4 w = {0.f, 0.f, 0.f, 0.f}, m = {0.f, 0.f, 0.f, 0.f};
  float yl = 0.f;

  f4 kA[8], qA[8]; float vA[8];
  f4 kB[8], qB[8]; float vB[8];

  auto step = [&](const f4& k, const f4& q, float v, int j32) {
    // ---- dot = w·k  (serial chain) ----
    f4 d = w * k;
    float dot = half_sum_all((d.x + d.y) + (d.z + d.w));
    float s = fmaf(C_S, dot, (-C_S) * v);
    f4 s4 = {s, s, s, s};
    // ---- m̂ = β m̂ + s k ; w = A w + m̂ ----
    m = __builtin_elementwise_fma(s4, k, bv * m);
    w = __builtin_elementwise_fma(av, w, m);
    // ---- y = w·q (off the serial chain) ----
    f4 e = w * q;
    float y = half_sum_all((e.x + e.y) + (e.z + e.w));
    yl = ((lane & 31) == j32) ? y : yl;  // j32 is a literal after unroll
  };

  // Prologue: two chunks in flight (48 loads).
  ISSUE_CHUNK(kA, qA, vA);
  ISSUE_CHUNK(kB, qB, vB);

  for (int it = 0; it < L_ / 32; ++it) {   // 256 windows of 32 steps
    WAITP;
#pragma unroll
    for (int j = 0; j < 8; ++j) step(kA[j], qA[j], vA[j], j);
    ISSUE_CHUNK(kA, qA, vA);
    WAITP;
#pragma unroll
    for (int j = 0; j < 8; ++j) step(kB[j], qB[j], vB[j], 8 + j);
    ISSUE_CHUNK(kB, qB, vB);
    WAITP;
#pragma unroll
    for (int j = 0; j < 8; ++j) step(kA[j], qA[j], vA[j], 16 + j);
    ISSUE_CHUNK(kA, qA, vA);
    WAITP;
#pragma unroll
    for (int j = 0; j < 8; ++j) step(kB[j], qB[j], vB[j], 24 + j);
    ISSUE_CHUNK(kB, qB, vB);
    // lane l (within each half) holds y for t = it*32 + l; coalesced-ish
    // strided store, one per window.
    *yst = yl;
    yst += 32 * D_;
  }
}

extern "C" void kernel_launch(void* const* d_in, const int* in_sizes, int n_in,
                              void* d_out, int out_size, void* d_ws, size_t ws_size,
                              hipStream_t stream) {
  const float* Q = (const float*)d_in[0];
  const float* K = (const float*)d_in[1];
  const float* V = (const float*)d_in[2];
  float* Y = (float*)d_out;
  dim3 grid(1024), block(64);
  hipLaunchKernelGGL(TitansMemory_188978561365_kernel, grid, block, 0, stream,
                     Q, K, V, Y);
}